// Round 4
// baseline (121.906 us; speedup 1.0000x reference)
//
#include <hip/hip_runtime.h>
#include <hip/hip_bf16.h>

#define N_POINTS 262144
#define N_NODES  8192
#define IN_C     256
#define HID      512
#define OUT_C    256
#define NB       16
#define MAXN     512
#define EPSV     1e-5f
#define NPB      16   // nodes per fused block

typedef __attribute__((ext_vector_type(8))) short short8;   // 8 bf16 = 4 VGPR
typedef __attribute__((ext_vector_type(4))) float f32x4;    // MFMA acc
#define MFMA16(a, b, c) __builtin_amdgcn_mfma_f32_16x16x32_bf16((a), (b), (c), 0, 0, 0)

// Fragment layout (gfx950 mfma_f32_16x16x32_bf16, m89-verified):
//   A[m][k]: m = lane&15, k = (lane>>4)*8 + j   (8 contiguous-k bf16 per lane)
//   B[k][n]: n = lane&15, k = (lane>>4)*8 + j
//   D[m][n]: n = lane&15, m = (lane>>4)*4 + reg

// ---------------------------------------------------------------------------
// Kernel 0 (prelude): blockIdx.x < 1024 -> node range boundaries from sorted
// fpb (thread per point, no binary search); else -> pack W fp32 -> fragment-
// packed bf16 so each MFMA B-fragment load is one 1 KB coalesced read.
// ---------------------------------------------------------------------------
__global__ __launch_bounds__(256) void prelude_k(
    const int* __restrict__ fpb, int* __restrict__ starts,
    const float* __restrict__ W1q, const float* __restrict__ W1k,
    const float* __restrict__ W2q, const float* __restrict__ W2k,
    __hip_bfloat16* __restrict__ P1q, __hip_bfloat16* __restrict__ P1k,
    __hip_bfloat16* __restrict__ P2q, __hip_bfloat16* __restrict__ P2k)
{
  if (blockIdx.x < 1024) {
    const int i = blockIdx.x * 256 + threadIdx.x;
    const int cur = fpb[i];
    const int prev = (i == 0) ? -1 : fpb[i - 1];
    for (int n = prev + 1; n <= cur; ++n) starts[n] = i;   // usually 0 or 1 iters
    if (i == N_POINTS - 1)
      for (int n = cur + 1; n <= N_NODES; ++n) starts[n] = N_POINTS;
    return;
  }
  const int bid = blockIdx.x - 1024;       // 0..255
  const int sel = bid >> 6;                // which weight
  const float* W; __hip_bfloat16* P; int N;
  switch (sel) {
    case 0:  W = W1q; P = P1q; N = HID;   break;
    case 1:  W = W1k; P = P1k; N = HID;   break;
    case 2:  W = W2q; P = P2q; N = OUT_C; break;
    default: W = W2k; P = P2k; N = OUT_C; break;
  }
  const int idx = (bid & 63) * 256 + threadIdx.x;  // (ks, nf, lane), 16384 total
  const int NF = N >> 4;
  const int lane = idx & 63;
  const int nf = (idx >> 6) % NF;
  const int ks = idx / (64 * NF);
  const int k0 = ks * 32 + (lane >> 4) * 8;
  const int n  = nf * 16 + (lane & 15);
  __hip_bfloat16 tmp[8];
  #pragma unroll
  for (int j = 0; j < 8; ++j) tmp[j] = __float2bfloat16(W[(size_t)(k0 + j) * N + n]);
  *(uint4*)(P + (size_t)idx * 8) = *(uint4*)tmp;
}

// ---------------------------------------------------------------------------
// Kernel 1: FUSED scatter-mean + both-head MLP.
// Block = 16 nodes, 256 threads (4 waves), 512 blocks (2 blocks/CU).
// Phase 1: wave w streams nodes [4w,4w+4) from x (one 1 KB row per wave-load),
//          fp32 accumulate, bf16 means -> LDS As[16][264]. No barriers inside.
// Phase 2: GEMM1 for q AND k (MFMA, B-frags from packed weights in L2),
//          bias + LN partials (shfl over 16 lanes) -> lnpq/lnpk.
// Phase 3: finish LN (cross-wave sums), relu, bf16 h -> Hq/Hk[16][520].
// Phase 4: GEMM2 both heads, +b2, write qo/ko.
// Total 3 __syncthreads.
// ---------------------------------------------------------------------------
__global__ __launch_bounds__(256, 2) void fused_mlp_k(
    const float* __restrict__ x, const int* __restrict__ starts,
    const __hip_bfloat16* __restrict__ P1q, const __hip_bfloat16* __restrict__ P2q,
    const float* __restrict__ b1q, const float* __restrict__ g1q,
    const float* __restrict__ be1q, const float* __restrict__ b2q,
    const __hip_bfloat16* __restrict__ P1k, const __hip_bfloat16* __restrict__ P2k,
    const float* __restrict__ b1k, const float* __restrict__ g1k,
    const float* __restrict__ be1k, const float* __restrict__ b2k,
    __hip_bfloat16* __restrict__ qo, __hip_bfloat16* __restrict__ ko)
{
  const int n0 = blockIdx.x * NPB;
  const int t = threadIdx.x;
  const int w = t >> 6, l = t & 63, lg = l >> 4, lm = l & 15;

  __shared__ __hip_bfloat16 As[NPB * 264];   //  8.4 KB (pad 8 -> 2-way banks, free)
  __shared__ __hip_bfloat16 Hq[NPB * 520];   // 16.6 KB
  __shared__ __hip_bfloat16 Hk[NPB * 520];   // 16.6 KB
  __shared__ float lnpq[4][NPB][2];
  __shared__ float lnpk[4][NPB][2];

  // ---- Phase 1: stream x, per-wave node means -> As ----
  #pragma unroll
  for (int i = 0; i < 4; ++i) {
    const int nl = w * 4 + i;
    const int node = n0 + nl;
    const int s_ = starts[node], e_ = starts[node + 1];
    float4 s = make_float4(0.f, 0.f, 0.f, 0.f);
    for (int r = s_; r < e_; ++r) {
      float4 v = *(const float4*)(x + (size_t)r * IN_C + l * 4);
      s.x += v.x; s.y += v.y; s.z += v.z; s.w += v.w;
    }
    const int cnt = e_ - s_;
    const float inv = cnt > 0 ? 1.0f / (float)cnt : 0.0f;
    __hip_bfloat16 o[4];
    o[0] = __float2bfloat16(s.x * inv);
    o[1] = __float2bfloat16(s.y * inv);
    o[2] = __float2bfloat16(s.z * inv);
    o[3] = __float2bfloat16(s.w * inv);
    *(uint2*)(As + nl * 264 + l * 4) = *(uint2*)o;
  }
  __syncthreads();

  // ---- Phase 2: GEMM1 both heads. Wave w owns cols [128w,128w+128). ----
  f32x4 aq[8], ak[8];
  #pragma unroll
  for (int nj = 0; nj < 8; ++nj)
    #pragma unroll
    for (int r = 0; r < 4; ++r) { aq[nj][r] = 0.f; ak[nj][r] = 0.f; }

  for (int ks = 0; ks < 8; ++ks) {
    short8 a = *(const short8*)(As + lm * 264 + ks * 32 + lg * 8);
    const __hip_bfloat16* bpq = P1q + ((size_t)(ks * 32 + w * 8) * 64 + l) * 8;
    const __hip_bfloat16* bpk = P1k + ((size_t)(ks * 32 + w * 8) * 64 + l) * 8;
    #pragma unroll
    for (int nj = 0; nj < 8; ++nj) {
      short8 bq = *(const short8*)(bpq + (size_t)nj * 512);
      short8 bk = *(const short8*)(bpk + (size_t)nj * 512);
      aq[nj] = MFMA16(a, bq, aq[nj]);
      ak[nj] = MFMA16(a, bk, ak[nj]);
    }
  }

  float b1vq[8], g1vq[8], e1vq[8], b1vk[8], g1vk[8], e1vk[8];
  #pragma unroll
  for (int nj = 0; nj < 8; ++nj) {
    const int c = w * 128 + nj * 16 + lm;
    b1vq[nj] = b1q[c]; g1vq[nj] = g1q[c]; e1vq[nj] = be1q[c];
    b1vk[nj] = b1k[c]; g1vk[nj] = g1k[c]; e1vk[nj] = be1k[c];
  }
  #pragma unroll
  for (int nj = 0; nj < 8; ++nj)
    #pragma unroll
    for (int r = 0; r < 4; ++r) { aq[nj][r] += b1vq[nj]; ak[nj][r] += b1vk[nj]; }

  #pragma unroll
  for (int r = 0; r < 4; ++r) {
    float sq = 0.f, qq = 0.f, sk = 0.f, qk = 0.f;
    #pragma unroll
    for (int nj = 0; nj < 8; ++nj) {
      const float vq = aq[nj][r], vk = ak[nj][r];
      sq += vq; qq += vq * vq;
      sk += vk; qk += vk * vk;
    }
    #pragma unroll
    for (int off = 1; off < 16; off <<= 1) {
      sq += __shfl_xor(sq, off); qq += __shfl_xor(qq, off);
      sk += __shfl_xor(sk, off); qk += __shfl_xor(qk, off);
    }
    if (lm == 0) {
      const int row = lg * 4 + r;
      lnpq[w][row][0] = sq; lnpq[w][row][1] = qq;
      lnpk[w][row][0] = sk; lnpk[w][row][1] = qk;
    }
  }
  __syncthreads();

  // ---- Phase 3: finish LN, relu, h -> Hq/Hk ----
  #pragma unroll
  for (int r = 0; r < 4; ++r) {
    const int row = lg * 4 + r;
    float Sq = 0.f, Qq = 0.f, Sk = 0.f, Qk = 0.f;
    #pragma unroll
    for (int w2 = 0; w2 < 4; ++w2) {
      Sq += lnpq[w2][row][0]; Qq += lnpq[w2][row][1];
      Sk += lnpk[w2][row][0]; Qk += lnpk[w2][row][1];
    }
    const float muq = Sq * (1.0f / HID);
    const float rsq = rsqrtf(Qq * (1.0f / HID) - muq * muq + EPSV);
    const float muk = Sk * (1.0f / HID);
    const float rsk = rsqrtf(Qk * (1.0f / HID) - muk * muk + EPSV);
    #pragma unroll
    for (int nj = 0; nj < 8; ++nj) {
      const float yq = (aq[nj][r] - muq) * rsq * g1vq[nj] + e1vq[nj];
      const float yk = (ak[nj][r] - muk) * rsk * g1vk[nj] + e1vk[nj];
      Hq[row * 520 + w * 128 + nj * 16 + lm] = __float2bfloat16(fmaxf(yq, 0.f));
      Hk[row * 520 + w * 128 + nj * 16 + lm] = __float2bfloat16(fmaxf(yk, 0.f));
    }
  }
  __syncthreads();

  // ---- Phase 4: GEMM2 both heads. Wave w owns cols [64w,64w+64). ----
  f32x4 cq[4], ck[4];
  #pragma unroll
  for (int nj = 0; nj < 4; ++nj)
    #pragma unroll
    for (int r = 0; r < 4; ++r) { cq[nj][r] = 0.f; ck[nj][r] = 0.f; }

  for (int ks = 0; ks < 16; ++ks) {
    short8 a2q = *(const short8*)(Hq + lm * 520 + ks * 32 + lg * 8);
    short8 a2k = *(const short8*)(Hk + lm * 520 + ks * 32 + lg * 8);
    const __hip_bfloat16* bpq2 = P2q + ((size_t)(ks * 16 + w * 4) * 64 + l) * 8;
    const __hip_bfloat16* bpk2 = P2k + ((size_t)(ks * 16 + w * 4) * 64 + l) * 8;
    #pragma unroll
    for (int nj = 0; nj < 4; ++nj) {
      short8 bq = *(const short8*)(bpq2 + (size_t)nj * 512);
      short8 bk = *(const short8*)(bpk2 + (size_t)nj * 512);
      cq[nj] = MFMA16(a2q, bq, cq[nj]);
      ck[nj] = MFMA16(a2k, bk, ck[nj]);
    }
  }

  float b2vq[4], b2vk[4];
  #pragma unroll
  for (int nj = 0; nj < 4; ++nj) {
    b2vq[nj] = b2q[w * 64 + nj * 16 + lm];
    b2vk[nj] = b2k[w * 64 + nj * 16 + lm];
  }
  #pragma unroll
  for (int nj = 0; nj < 4; ++nj)
    #pragma unroll
    for (int r = 0; r < 4; ++r) {
      const int row = n0 + lg * 4 + r;
      const int col = w * 64 + nj * 16 + lm;
      qo[(size_t)row * OUT_C + col] = __float2bfloat16(cq[nj][r] + b2vq[nj]);
      ko[(size_t)row * OUT_C + col] = __float2bfloat16(ck[nj][r] + b2vk[nj]);
    }
}

// ---------------------------------------------------------------------------
// Kernel 2: out[b] = q_b @ k_b^T, fp32 out. 128x128 tile, 4 waves 2x2.
// No LDS: both operands are contiguous 16 B fragments from L2-resident q/k.
// ---------------------------------------------------------------------------
__global__ __launch_bounds__(256) void bmm_k(
    const __hip_bfloat16* __restrict__ q, const __hip_bfloat16* __restrict__ k,
    float* __restrict__ out)
{
  const int b  = blockIdx.z;
  const int n0 = blockIdx.x * 128;
  const int m0 = blockIdx.y * 128;
  const int t = threadIdx.x;
  const int w = t >> 6, l = t & 63, lg = l >> 4, lm = l & 15;
  const int wm = w >> 1, wn = w & 1;

  const __hip_bfloat16* qb = q + ((size_t)b * MAXN + n0 + wm * 64) * OUT_C;
  const __hip_bfloat16* kb = k + ((size_t)b * MAXN + m0 + wn * 64) * OUT_C;

  f32x4 acc[4][4];
  #pragma unroll
  for (int mi = 0; mi < 4; ++mi)
    #pragma unroll
    for (int nj = 0; nj < 4; ++nj)
      #pragma unroll
      for (int r = 0; r < 4; ++r) acc[mi][nj][r] = 0.f;

  for (int ks = 0; ks < 8; ++ks) {
    short8 a[4], bb[4];
    #pragma unroll
    for (int mi = 0; mi < 4; ++mi)
      a[mi] = *(const short8*)(qb + (size_t)(mi * 16 + lm) * OUT_C + ks * 32 + lg * 8);
    #pragma unroll
    for (int nj = 0; nj < 4; ++nj)
      bb[nj] = *(const short8*)(kb + (size_t)(nj * 16 + lm) * OUT_C + ks * 32 + lg * 8);
    #pragma unroll
    for (int mi = 0; mi < 4; ++mi)
      #pragma unroll
      for (int nj = 0; nj < 4; ++nj)
        acc[mi][nj] = MFMA16(a[mi], bb[nj], acc[mi][nj]);
  }

  #pragma unroll
  for (int mi = 0; mi < 4; ++mi)
    #pragma unroll
    for (int nj = 0; nj < 4; ++nj)
      #pragma unroll
      for (int r = 0; r < 4; ++r) {
        const int nrow = n0 + wm * 64 + mi * 16 + lg * 4 + r;  // q node (row)
        const int mcol = m0 + wn * 64 + nj * 16 + lm;          // k node (col)
        out[((size_t)b * MAXN + nrow) * MAXN + mcol] = acc[mi][nj][r];
      }
}

// ---------------------------------------------------------------------------
extern "C" void kernel_launch(void* const* d_in, const int* in_sizes, int n_in,
                              void* d_out, int out_size, void* d_ws, size_t ws_size,
                              hipStream_t stream)
{
  const float* x   = (const float*)d_in[0];
  const int*   fpb = (const int*)d_in[1];
  // d_in[2]=g_node_batches (repeat(arange(16),512) -> pad/split is identity
  // reshape), d_in[3]=num_graphs, d_in[4]=max_nodes.
  const float* Wq_w1  = (const float*)d_in[5];
  const float* Wq_b1  = (const float*)d_in[6];
  const float* Wq_g1  = (const float*)d_in[7];
  const float* Wq_be1 = (const float*)d_in[8];
  const float* Wq_w2  = (const float*)d_in[9];
  const float* Wq_b2  = (const float*)d_in[10];
  const float* Wk_w1  = (const float*)d_in[11];
  const float* Wk_b1  = (const float*)d_in[12];
  const float* Wk_g1  = (const float*)d_in[13];
  const float* Wk_be1 = (const float*)d_in[14];
  const float* Wk_w2  = (const float*)d_in[15];
  const float* Wk_b2  = (const float*)d_in[16];

  __hip_bfloat16* ws = (__hip_bfloat16*)d_ws;
  __hip_bfloat16* P1q  = ws;                 // 131072 bf16 each
  __hip_bfloat16* P1k  = P1q + 131072;
  __hip_bfloat16* P2q  = P1k + 131072;
  __hip_bfloat16* P2k  = P2q + 131072;
  __hip_bfloat16* qo   = P2k + 131072;       // 8192*256
  __hip_bfloat16* ko   = qo + 2097152;
  int* starts = (int*)(ko + 2097152);        // 8193 ints
  float* out = (float*)d_out;

  prelude_k<<<1280, 256, 0, stream>>>(fpb, starts,
      Wq_w1, Wk_w1, Wq_w2, Wk_w2, P1q, P1k, P2q, P2k);
  fused_mlp_k<<<N_NODES / NPB, 256, 0, stream>>>(
      x, starts, P1q, P2q, Wq_b1, Wq_g1, Wq_be1, Wq_b2,
      P1k, P2k, Wk_b1, Wk_g1, Wk_be1, Wk_b2, qo, ko);
  bmm_k<<<dim3(4, 4, NB), 256, 0, stream>>>(qo, ko, out);
}

// Round 5
// 95.509 us; speedup vs baseline: 1.2764x; 1.2764x over previous
//
#include <hip/hip_runtime.h>
#include <hip/hip_bf16.h>

#define N_POINTS 262144
#define N_NODES  8192
#define IN_C     256
#define HID      512
#define OUT_C    256
#define NB       16
#define MAXN     512
#define EPSV     1e-5f
#define NPB      32   // rows (nodes) per MLP block

typedef __attribute__((ext_vector_type(8))) short short8;   // 8 bf16 = 4 VGPR
typedef __attribute__((ext_vector_type(4))) float f32x4;    // MFMA acc
#define MFMA16(a, b, c) __builtin_amdgcn_mfma_f32_16x16x32_bf16((a), (b), (c), 0, 0, 0)

// Fragment layout (gfx950 mfma_f32_16x16x32_bf16, m89-verified):
//   A[m][k]: m = lane&15, k = (lane>>4)*8 + j   (8 contiguous-k bf16 per lane)
//   B[k][n]: n = lane&15, k = (lane>>4)*8 + j
//   D[m][n]: n = lane&15, m = (lane>>4)*4 + reg

// ---------------------------------------------------------------------------
// Kernel 0 (prelude): blockIdx.x < 1024 -> node range boundaries from sorted
// fpb (thread per point); else pack W fp32 -> fragment-packed bf16 so each
// MFMA B-fragment load is one 1 KB coalesced read.
// ---------------------------------------------------------------------------
__global__ __launch_bounds__(256) void prelude_k(
    const int* __restrict__ fpb, int* __restrict__ starts,
    const float* __restrict__ W1q, const float* __restrict__ W1k,
    const float* __restrict__ W2q, const float* __restrict__ W2k,
    __hip_bfloat16* __restrict__ P1q, __hip_bfloat16* __restrict__ P1k,
    __hip_bfloat16* __restrict__ P2q, __hip_bfloat16* __restrict__ P2k)
{
  if (blockIdx.x < 1024) {
    const int i = blockIdx.x * 256 + threadIdx.x;
    const int cur = fpb[i];
    const int prev = (i == 0) ? -1 : fpb[i - 1];
    for (int n = prev + 1; n <= cur; ++n) starts[n] = i;   // usually 0 or 1 iters
    if (i == N_POINTS - 1)
      for (int n = cur + 1; n <= N_NODES; ++n) starts[n] = N_POINTS;
    return;
  }
  const int bid = blockIdx.x - 1024;       // 0..255
  const int sel = bid >> 6;                // which weight
  const float* W; __hip_bfloat16* P; int N;
  switch (sel) {
    case 0:  W = W1q; P = P1q; N = HID;   break;
    case 1:  W = W1k; P = P1k; N = HID;   break;
    case 2:  W = W2q; P = P2q; N = OUT_C; break;
    default: W = W2k; P = P2k; N = OUT_C; break;
  }
  const int idx = (bid & 63) * 256 + threadIdx.x;  // (ks, nf, lane), 16384 total
  const int NF = N >> 4;
  const int lane = idx & 63;
  const int nf = (idx >> 6) % NF;
  const int ks = idx / (64 * NF);
  const int k0 = ks * 32 + (lane >> 4) * 8;
  const int n  = nf * 16 + (lane & 15);
  __hip_bfloat16 tmp[8];
  #pragma unroll
  for (int j = 0; j < 8; ++j) tmp[j] = __float2bfloat16(W[(size_t)(k0 + j) * N + n]);
  *(uint4*)(P + (size_t)idx * 8) = *(uint4*)tmp;
}

// ---------------------------------------------------------------------------
// Kernel 1: scatter-mean, float4 loads (16 B/lane), 2-deep pipelined rows.
// One node per block, 256 threads (4 waves); wave w handles rows == w (mod 4),
// two independent row-streams (r, r+4) per iteration for 2 loads in flight.
// ---------------------------------------------------------------------------
__global__ __launch_bounds__(256) void scatter_mean_k(
    const float* __restrict__ x, const int* __restrict__ starts,
    __hip_bfloat16* __restrict__ mean)
{
  const int node = blockIdx.x;
  const int start = starts[node];
  const int end   = starts[node + 1];
  const int t  = threadIdx.x;
  const int c4 = t & 63;   // float4 column
  const int rr = t >> 6;   // row phase 0..3

  float4 s0 = make_float4(0.f, 0.f, 0.f, 0.f);
  float4 s1 = make_float4(0.f, 0.f, 0.f, 0.f);
  int r = start + rr;
  for (; r + 8 <= end; r += 8) {
    float4 v0 = *(const float4*)(x + (size_t)r * IN_C + c4 * 4);
    float4 v1 = *(const float4*)(x + (size_t)(r + 4) * IN_C + c4 * 4);
    s0.x += v0.x; s0.y += v0.y; s0.z += v0.z; s0.w += v0.w;
    s1.x += v1.x; s1.y += v1.y; s1.z += v1.z; s1.w += v1.w;
  }
  for (; r < end; r += 4) {
    float4 v = *(const float4*)(x + (size_t)r * IN_C + c4 * 4);
    s0.x += v.x; s0.y += v.y; s0.z += v.z; s0.w += v.w;
  }
  s0.x += s1.x; s0.y += s1.y; s0.z += s1.z; s0.w += s1.w;

  __shared__ float4 red[256];
  red[t] = s0;
  __syncthreads();
  if (t < 64) {
    float4 a = red[t], b = red[t + 64], c = red[t + 128], d = red[t + 192];
    const int cnt = end - start;
    const float inv = cnt > 0 ? 1.0f / (float)cnt : 0.0f;
    __hip_bfloat16 o[4];
    o[0] = __float2bfloat16((a.x + b.x + c.x + d.x) * inv);
    o[1] = __float2bfloat16((a.y + b.y + c.y + d.y) * inv);
    o[2] = __float2bfloat16((a.z + b.z + c.z + d.z) * inv);
    o[3] = __float2bfloat16((a.w + b.w + c.w + d.w) * inv);
    *(uint2*)(mean + (size_t)node * IN_C + t * 4) = *(uint2*)o;
  }
}

// ---------------------------------------------------------------------------
// Kernel 2: both-head fused MLP: {qo,ko} = LN_relu(mean@W1+b1)@W2 + b2 (bf16).
// 512 threads = 8 waves; waves 0-3 head q, 4-7 head k; wave owns col-quarter
// c = w&3: GEMM1 cols [128c,128c+128), GEMM2 cols [64c,64c+64). 32 rows/block,
// 256 blocks -> 1 block/CU, 2 waves/SIMD (TLP hides L2 fragment-load latency).
// ---------------------------------------------------------------------------
__global__ __launch_bounds__(512, 2) void mlp_fused_k(
    const __hip_bfloat16* __restrict__ mean,
    const __hip_bfloat16* __restrict__ P1q, const __hip_bfloat16* __restrict__ P2q,
    const float* __restrict__ b1q, const float* __restrict__ g1q,
    const float* __restrict__ be1q, const float* __restrict__ b2q,
    const __hip_bfloat16* __restrict__ P1k, const __hip_bfloat16* __restrict__ P2k,
    const float* __restrict__ b1k, const float* __restrict__ g1k,
    const float* __restrict__ be1k, const float* __restrict__ b2k,
    __hip_bfloat16* __restrict__ qo, __hip_bfloat16* __restrict__ ko)
{
  const int n0 = blockIdx.x * NPB;
  const int t = threadIdx.x;
  const int w = t >> 6, l = t & 63, lg = l >> 4, lm = l & 15;
  const int h = w >> 2;      // head: 0=q 1=k
  const int c = w & 3;       // column quarter

  const __hip_bfloat16* P1 = h ? P1k : P1q;
  const __hip_bfloat16* P2 = h ? P2k : P2q;
  const float* b1  = h ? b1k  : b1q;
  const float* g1  = h ? g1k  : g1q;
  const float* be1 = h ? be1k : be1q;
  const float* b2  = h ? b2k  : b2q;
  __hip_bfloat16* out = h ? ko : qo;

  __shared__ __hip_bfloat16 As[NPB * 264];       // 16.9 KB
  __shared__ __hip_bfloat16 Hs[2][NPB * 520];    // 66.6 KB
  __shared__ float lnp[8][NPB][2];               //  2 KB

  // ---- stage mean tile [32][256] -> As ----
  #pragma unroll
  for (int it = 0; it < 2; ++it) {
    const int idx = t + it * 512;          // 1024 x 8 bf16
    const int r = idx >> 5, c8 = idx & 31;
    uint4 v = *(const uint4*)(mean + (size_t)(n0 + r) * IN_C + c8 * 8);
    *(uint4*)(As + r * 264 + c8 * 8) = v;
  }
  __syncthreads();

  // ---- GEMM1: C1[32][128c..] = A[32][256] x W1[256][128c..] ----
  f32x4 acc1[2][8];
  #pragma unroll
  for (int mi = 0; mi < 2; ++mi)
    #pragma unroll
    for (int nj = 0; nj < 8; ++nj)
      #pragma unroll
      for (int r = 0; r < 4; ++r) acc1[mi][nj][r] = 0.f;

  for (int ks = 0; ks < 8; ++ks) {
    short8 a0 = *(const short8*)(As + lm * 264 + ks * 32 + lg * 8);
    short8 a1 = *(const short8*)(As + (16 + lm) * 264 + ks * 32 + lg * 8);
    const __hip_bfloat16* bp = P1 + ((size_t)(ks * 32 + c * 8) * 64 + l) * 8;
    #pragma unroll
    for (int nj = 0; nj < 8; ++nj) {
      short8 b = *(const short8*)(bp + (size_t)nj * 512);
      acc1[0][nj] = MFMA16(a0, b, acc1[0][nj]);
      acc1[1][nj] = MFMA16(a1, b, acc1[1][nj]);
    }
  }

  float b1v[8], g1v[8], e1v[8];
  #pragma unroll
  for (int nj = 0; nj < 8; ++nj) {
    const int col = c * 128 + nj * 16 + lm;
    b1v[nj] = b1[col]; g1v[nj] = g1[col]; e1v[nj] = be1[col];
  }
  #pragma unroll
  for (int mi = 0; mi < 2; ++mi)
    #pragma unroll
    for (int nj = 0; nj < 8; ++nj)
      #pragma unroll
      for (int r = 0; r < 4; ++r) acc1[mi][nj][r] += b1v[nj];

  // LN partials over this wave's 128 cols (16-lane shfl reduce)
  #pragma unroll
  for (int mi = 0; mi < 2; ++mi)
    #pragma unroll
    for (int r = 0; r < 4; ++r) {
      float s = 0.f, q = 0.f;
      #pragma unroll
      for (int nj = 0; nj < 8; ++nj) {
        const float v = acc1[mi][nj][r];
        s += v; q += v * v;
      }
      #pragma unroll
      for (int off = 1; off < 16; off <<= 1) {
        s += __shfl_xor(s, off);
        q += __shfl_xor(q, off);
      }
      if (lm == 0) {
        const int row = mi * 16 + lg * 4 + r;
        lnp[w][row][0] = s;
        lnp[w][row][1] = q;
      }
    }
  __syncthreads();

  // ---- finish LN (combine 4 waves of this head), relu, h -> Hs[h] ----
  #pragma unroll
  for (int mi = 0; mi < 2; ++mi)
    #pragma unroll
    for (int r = 0; r < 4; ++r) {
      const int row = mi * 16 + lg * 4 + r;
      float S = 0.f, Q = 0.f;
      #pragma unroll
      for (int w2 = 0; w2 < 4; ++w2) {
        S += lnp[h * 4 + w2][row][0];
        Q += lnp[h * 4 + w2][row][1];
      }
      const float mu = S * (1.0f / HID);
      const float rs = rsqrtf(Q * (1.0f / HID) - mu * mu + EPSV);
      #pragma unroll
      for (int nj = 0; nj < 8; ++nj) {
        const float y = (acc1[mi][nj][r] - mu) * rs * g1v[nj] + e1v[nj];
        Hs[h][row * 520 + c * 128 + nj * 16 + lm] = __float2bfloat16(fmaxf(y, 0.f));
      }
    }
  __syncthreads();

  // ---- GEMM2: C2[32][64c..] = h[32][512] x W2[512][64c..] ----
  f32x4 acc2[2][4];
  #pragma unroll
  for (int mi = 0; mi < 2; ++mi)
    #pragma unroll
    for (int nj = 0; nj < 4; ++nj)
      #pragma unroll
      for (int r = 0; r < 4; ++r) acc2[mi][nj][r] = 0.f;

  for (int ks = 0; ks < 16; ++ks) {
    short8 a0 = *(const short8*)(Hs[h] + lm * 520 + ks * 32 + lg * 8);
    short8 a1 = *(const short8*)(Hs[h] + (16 + lm) * 520 + ks * 32 + lg * 8);
    const __hip_bfloat16* bp = P2 + ((size_t)(ks * 16 + c * 4) * 64 + l) * 8;
    #pragma unroll
    for (int nj = 0; nj < 4; ++nj) {
      short8 b = *(const short8*)(bp + (size_t)nj * 512);
      acc2[0][nj] = MFMA16(a0, b, acc2[0][nj]);
      acc2[1][nj] = MFMA16(a1, b, acc2[1][nj]);
    }
  }

  float b2v[4];
  #pragma unroll
  for (int nj = 0; nj < 4; ++nj) b2v[nj] = b2[c * 64 + nj * 16 + lm];
  #pragma unroll
  for (int mi = 0; mi < 2; ++mi)
    #pragma unroll
    for (int nj = 0; nj < 4; ++nj)
      #pragma unroll
      for (int r = 0; r < 4; ++r) {
        const int row = n0 + mi * 16 + lg * 4 + r;
        const int col = c * 64 + nj * 16 + lm;
        out[(size_t)row * OUT_C + col] = __float2bfloat16(acc2[mi][nj][r] + b2v[nj]);
      }
}

// ---------------------------------------------------------------------------
// Kernel 3: out[b] = q_b @ k_b^T, fp32 out. 64x64 tile, 1024 blocks of 4
// waves -> 4 blocks/CU, 4 waves/SIMD. Wave w computes rows [16w,16w+16).
// Operands are contiguous 16 B fragments from L2-resident q/k (no LDS).
// ---------------------------------------------------------------------------
__global__ __launch_bounds__(256, 4) void bmm_k(
    const __hip_bfloat16* __restrict__ q, const __hip_bfloat16* __restrict__ k,
    float* __restrict__ out)
{
  const int b  = blockIdx.z;
  const int n0 = blockIdx.x * 64;
  const int m0 = blockIdx.y * 64;
  const int t = threadIdx.x;
  const int w = t >> 6, l = t & 63, lg = l >> 4, lm = l & 15;

  const __hip_bfloat16* qb = q + ((size_t)b * MAXN + n0 + w * 16) * OUT_C;
  const __hip_bfloat16* kb = k + ((size_t)b * MAXN + m0) * OUT_C;

  f32x4 acc[4];
  #pragma unroll
  for (int nj = 0; nj < 4; ++nj)
    #pragma unroll
    for (int r = 0; r < 4; ++r) acc[nj][r] = 0.f;

  for (int ks = 0; ks < 8; ++ks) {
    short8 a = *(const short8*)(qb + (size_t)lm * OUT_C + ks * 32 + lg * 8);
    #pragma unroll
    for (int nj = 0; nj < 4; ++nj) {
      short8 bb = *(const short8*)(kb + (size_t)(nj * 16 + lm) * OUT_C + ks * 32 + lg * 8);
      acc[nj] = MFMA16(a, bb, acc[nj]);
    }
  }

  #pragma unroll
  for (int nj = 0; nj < 4; ++nj)
    #pragma unroll
    for (int r = 0; r < 4; ++r) {
      const int nrow = n0 + w * 16 + lg * 4 + r;   // q node (output row)
      const int mcol = m0 + nj * 16 + lm;          // k node (output col)
      out[((size_t)b * MAXN + nrow) * MAXN + mcol] = acc[nj][r];
    }
}

// ---------------------------------------------------------------------------
extern "C" void kernel_launch(void* const* d_in, const int* in_sizes, int n_in,
                              void* d_out, int out_size, void* d_ws, size_t ws_size,
                              hipStream_t stream)
{
  const float* x   = (const float*)d_in[0];
  const int*   fpb = (const int*)d_in[1];
  // d_in[2]=g_node_batches (repeat(arange(16),512) -> pad/split is identity
  // reshape), d_in[3]=num_graphs, d_in[4]=max_nodes.
  const float* Wq_w1  = (const float*)d_in[5];
  const float* Wq_b1  = (const float*)d_in[6];
  const float* Wq_g1  = (const float*)d_in[7];
  const float* Wq_be1 = (const float*)d_in[8];
  const float* Wq_w2  = (const float*)d_in[9];
  const float* Wq_b2  = (const float*)d_in[10];
  const float* Wk_w1  = (const float*)d_in[11];
  const float* Wk_b1  = (const float*)d_in[12];
  const float* Wk_g1  = (const float*)d_in[13];
  const float* Wk_be1 = (const float*)d_in[14];
  const float* Wk_w2  = (const float*)d_in[15];
  const float* Wk_b2  = (const float*)d_in[16];

  __hip_bfloat16* ws = (__hip_bfloat16*)d_ws;
  __hip_bfloat16* P1q  = ws;                 // 131072 bf16 each
  __hip_bfloat16* P1k  = P1q + 131072;
  __hip_bfloat16* P2q  = P1k + 131072;
  __hip_bfloat16* P2k  = P2q + 131072;
  __hip_bfloat16* mean = P2k + 131072;       // 8192*256
  __hip_bfloat16* qo   = mean + 2097152;     // 8192*256
  __hip_bfloat16* ko   = qo + 2097152;
  int* starts = (int*)(ko + 2097152);        // 8193 ints
  float* out = (float*)d_out;

  prelude_k<<<1280, 256, 0, stream>>>(fpb, starts,
      Wq_w1, Wk_w1, Wq_w2, Wk_w2, P1q, P1k, P2q, P2k);
  scatter_mean_k<<<N_NODES, 256, 0, stream>>>(x, starts, mean);
  mlp_fused_k<<<N_NODES / NPB, 512, 0, stream>>>(
      mean, P1q, P2q, Wq_b1, Wq_g1, Wq_be1, Wq_b2,
      P1k, P2k, Wk_b1, Wk_g1, Wk_be1, Wk_b2, qo, ko);
  bmm_k<<<dim3(8, 8, NB), 256, 0, stream>>>(qo, ko, out);
}

// Round 6
// 89.918 us; speedup vs baseline: 1.3557x; 1.0622x over previous
//
#include <hip/hip_runtime.h>
#include <hip/hip_bf16.h>

#define N_POINTS 262144
#define N_NODES  8192
#define IN_C     256
#define HID      512
#define OUT_C    256
#define NB       16
#define MAXN     512
#define EPSV     1e-5f
#define NPB      16   // nodes per fused block

typedef __attribute__((ext_vector_type(8))) short short8;   // 8 bf16 = 4 VGPR
typedef __attribute__((ext_vector_type(4))) float f32x4;    // MFMA acc
#define MFMA16(a, b, c) __builtin_amdgcn_mfma_f32_16x16x32_bf16((a), (b), (c), 0, 0, 0)

// Fragment layout (gfx950 mfma_f32_16x16x32_bf16, m89-verified):
//   A[m][k]: m = lane&15, k = (lane>>4)*8 + j   (8 contiguous-k bf16 per lane)
//   B[k][n]: n = lane&15, k = (lane>>4)*8 + j
//   D[m][n]: n = lane&15, m = (lane>>4)*4 + reg

// ---------------------------------------------------------------------------
// Kernel 0 (prelude): blockIdx.x < 1024 -> node range boundaries from sorted
// fpb (thread per point); else pack W fp32 -> fragment-packed bf16 so each
// MFMA B-fragment load is one 1 KB coalesced read.
// ---------------------------------------------------------------------------
__global__ __launch_bounds__(256) void prelude_k(
    const int* __restrict__ fpb, int* __restrict__ starts,
    const float* __restrict__ W1q, const float* __restrict__ W1k,
    const float* __restrict__ W2q, const float* __restrict__ W2k,
    __hip_bfloat16* __restrict__ P1q, __hip_bfloat16* __restrict__ P1k,
    __hip_bfloat16* __restrict__ P2q, __hip_bfloat16* __restrict__ P2k)
{
  if (blockIdx.x < 1024) {
    const int i = blockIdx.x * 256 + threadIdx.x;
    const int cur = fpb[i];
    const int prev = (i == 0) ? -1 : fpb[i - 1];
    for (int n = prev + 1; n <= cur; ++n) starts[n] = i;   // usually 0 or 1 iters
    if (i == N_POINTS - 1)
      for (int n = cur + 1; n <= N_NODES; ++n) starts[n] = N_POINTS;
    return;
  }
  const int bid = blockIdx.x - 1024;       // 0..255
  const int sel = bid >> 6;                // which weight
  const float* W; __hip_bfloat16* P; int N;
  switch (sel) {
    case 0:  W = W1q; P = P1q; N = HID;   break;
    case 1:  W = W1k; P = P1k; N = HID;   break;
    case 2:  W = W2q; P = P2q; N = OUT_C; break;
    default: W = W2k; P = P2k; N = OUT_C; break;
  }
  const int idx = (bid & 63) * 256 + threadIdx.x;  // (ks, nf, lane), 16384 total
  const int NF = N >> 4;
  const int lane = idx & 63;
  const int nf = (idx >> 6) % NF;
  const int ks = idx / (64 * NF);
  const int k0 = ks * 32 + (lane >> 4) * 8;
  const int n  = nf * 16 + (lane & 15);
  __hip_bfloat16 tmp[8];
  #pragma unroll
  for (int j = 0; j < 8; ++j) tmp[j] = __float2bfloat16(W[(size_t)(k0 + j) * N + n]);
  *(uint4*)(P + (size_t)idx * 8) = *(uint4*)tmp;
}

// ---------------------------------------------------------------------------
// Kernel 1: FUSED scatter-mean + both-head MLP.  512 blocks x 512 thr (8 waves),
// 16 nodes/block, LDS ~44 KB -> 2 blocks/CU = 16 waves/CU.
// Stream: wave w owns nodes {2w, 2w+1}; 4-deep row pipeline (4 KB in flight
// per wave; 64 KB/CU >> 15 KB latency-BW product) -> means direct to LDS.
// Then GEMM1 both heads (wave = head h x col-quarter c), LN, GEMM2, store q/k.
// Blocks finishing their stream early run MFMA under other blocks' streams.
// ---------------------------------------------------------------------------
__global__ __launch_bounds__(512, 4) void fused_mlp_k(
    const float* __restrict__ x, const int* __restrict__ starts,
    const __hip_bfloat16* __restrict__ P1q, const __hip_bfloat16* __restrict__ P2q,
    const float* __restrict__ b1q, const float* __restrict__ g1q,
    const float* __restrict__ be1q, const float* __restrict__ b2q,
    const __hip_bfloat16* __restrict__ P1k, const __hip_bfloat16* __restrict__ P2k,
    const float* __restrict__ b1k, const float* __restrict__ g1k,
    const float* __restrict__ be1k, const float* __restrict__ b2k,
    __hip_bfloat16* __restrict__ qo, __hip_bfloat16* __restrict__ ko)
{
  const int n0 = blockIdx.x * NPB;
  const int t = threadIdx.x;
  const int w = t >> 6, l = t & 63, lg = l >> 4, lm = l & 15;
  const int h = w >> 2;      // head: 0=q 1=k
  const int c = w & 3;       // column quarter

  const __hip_bfloat16* P1 = h ? P1k : P1q;
  const __hip_bfloat16* P2 = h ? P2k : P2q;
  const float* b1  = h ? b1k  : b1q;
  const float* g1  = h ? g1k  : g1q;
  const float* be1 = h ? be1k : be1q;
  const float* b2  = h ? b2k  : b2q;
  __hip_bfloat16* out = h ? ko : qo;

  __shared__ __hip_bfloat16 As[NPB * 264];       //  8.4 KB
  __shared__ __hip_bfloat16 Hs[2][NPB * 520];    // 33.3 KB
  __shared__ float lnp[8][NPB][2];               //  1 KB

  // ---- Phase 1: stream x rows, per-wave node means -> As ----
  #pragma unroll
  for (int i = 0; i < 2; ++i) {
    const int nl = w * 2 + i;
    const int node = n0 + nl;
    const int s_ = starts[node], e_ = starts[node + 1];
    float4 a0 = make_float4(0.f, 0.f, 0.f, 0.f);
    float4 a1 = a0, a2 = a0, a3 = a0;
    int r = s_;
    for (; r + 4 <= e_; r += 4) {      // 4 independent 1 KB row-loads in flight
      float4 v0 = *(const float4*)(x + (size_t)(r + 0) * IN_C + l * 4);
      float4 v1 = *(const float4*)(x + (size_t)(r + 1) * IN_C + l * 4);
      float4 v2 = *(const float4*)(x + (size_t)(r + 2) * IN_C + l * 4);
      float4 v3 = *(const float4*)(x + (size_t)(r + 3) * IN_C + l * 4);
      a0.x += v0.x; a0.y += v0.y; a0.z += v0.z; a0.w += v0.w;
      a1.x += v1.x; a1.y += v1.y; a1.z += v1.z; a1.w += v1.w;
      a2.x += v2.x; a2.y += v2.y; a2.z += v2.z; a2.w += v2.w;
      a3.x += v3.x; a3.y += v3.y; a3.z += v3.z; a3.w += v3.w;
    }
    for (; r < e_; ++r) {
      float4 v = *(const float4*)(x + (size_t)r * IN_C + l * 4);
      a0.x += v.x; a0.y += v.y; a0.z += v.z; a0.w += v.w;
    }
    a0.x += a1.x + a2.x + a3.x;
    a0.y += a1.y + a2.y + a3.y;
    a0.z += a1.z + a2.z + a3.z;
    a0.w += a1.w + a2.w + a3.w;
    const int cnt = e_ - s_;
    const float inv = cnt > 0 ? 1.0f / (float)cnt : 0.0f;
    __hip_bfloat16 o[4];
    o[0] = __float2bfloat16(a0.x * inv);
    o[1] = __float2bfloat16(a0.y * inv);
    o[2] = __float2bfloat16(a0.z * inv);
    o[3] = __float2bfloat16(a0.w * inv);
    *(uint2*)(As + nl * 264 + l * 4) = *(uint2*)o;
  }
  __syncthreads();

  // ---- Phase 2: GEMM1: C1[16][128c..] = A[16][256] x W1[256][128c..] ----
  f32x4 acc1[8];
  #pragma unroll
  for (int nj = 0; nj < 8; ++nj)
    #pragma unroll
    for (int r = 0; r < 4; ++r) acc1[nj][r] = 0.f;

  for (int ks = 0; ks < 8; ++ks) {
    short8 a = *(const short8*)(As + lm * 264 + ks * 32 + lg * 8);
    const __hip_bfloat16* bp = P1 + ((size_t)(ks * 32 + c * 8) * 64 + l) * 8;
    #pragma unroll
    for (int nj = 0; nj < 8; ++nj) {
      short8 b = *(const short8*)(bp + (size_t)nj * 512);
      acc1[nj] = MFMA16(a, b, acc1[nj]);
    }
  }

  float b1v[8], g1v[8], e1v[8];
  #pragma unroll
  for (int nj = 0; nj < 8; ++nj) {
    const int col = c * 128 + nj * 16 + lm;
    b1v[nj] = b1[col]; g1v[nj] = g1[col]; e1v[nj] = be1[col];
  }
  #pragma unroll
  for (int nj = 0; nj < 8; ++nj)
    #pragma unroll
    for (int r = 0; r < 4; ++r) acc1[nj][r] += b1v[nj];

  // LN partials over this wave's 128 cols (16-lane shfl reduce)
  #pragma unroll
  for (int r = 0; r < 4; ++r) {
    float s = 0.f, q = 0.f;
    #pragma unroll
    for (int nj = 0; nj < 8; ++nj) {
      const float v = acc1[nj][r];
      s += v; q += v * v;
    }
    #pragma unroll
    for (int off = 1; off < 16; off <<= 1) {
      s += __shfl_xor(s, off);
      q += __shfl_xor(q, off);
    }
    if (lm == 0) {
      const int row = lg * 4 + r;
      lnp[w][row][0] = s;
      lnp[w][row][1] = q;
    }
  }
  __syncthreads();

  // ---- Phase 3: finish LN (combine this head's 4 waves), relu, h -> Hs[h] ----
  #pragma unroll
  for (int r = 0; r < 4; ++r) {
    const int row = lg * 4 + r;
    float S = 0.f, Q = 0.f;
    #pragma unroll
    for (int w2 = 0; w2 < 4; ++w2) {
      S += lnp[h * 4 + w2][row][0];
      Q += lnp[h * 4 + w2][row][1];
    }
    const float mu = S * (1.0f / HID);
    const float rs = rsqrtf(Q * (1.0f / HID) - mu * mu + EPSV);
    #pragma unroll
    for (int nj = 0; nj < 8; ++nj) {
      const float y = (acc1[nj][r] - mu) * rs * g1v[nj] + e1v[nj];
      Hs[h][row * 520 + c * 128 + nj * 16 + lm] = __float2bfloat16(fmaxf(y, 0.f));
    }
  }
  __syncthreads();

  // ---- Phase 4: GEMM2: C2[16][64c..] = h[16][512] x W2[512][64c..] ----
  f32x4 acc2[4];
  #pragma unroll
  for (int nj = 0; nj < 4; ++nj)
    #pragma unroll
    for (int r = 0; r < 4; ++r) acc2[nj][r] = 0.f;

  for (int ks = 0; ks < 16; ++ks) {
    short8 a = *(const short8*)(Hs[h] + lm * 520 + ks * 32 + lg * 8);
    const __hip_bfloat16* bp = P2 + ((size_t)(ks * 16 + c * 4) * 64 + l) * 8;
    #pragma unroll
    for (int nj = 0; nj < 4; ++nj) {
      short8 b = *(const short8*)(bp + (size_t)nj * 512);
      acc2[nj] = MFMA16(a, b, acc2[nj]);
    }
  }

  float b2v[4];
  #pragma unroll
  for (int nj = 0; nj < 4; ++nj) b2v[nj] = b2[c * 64 + nj * 16 + lm];
  #pragma unroll
  for (int nj = 0; nj < 4; ++nj)
    #pragma unroll
    for (int r = 0; r < 4; ++r) {
      const int row = n0 + lg * 4 + r;
      const int col = c * 64 + nj * 16 + lm;
      out[(size_t)row * OUT_C + col] = __float2bfloat16(acc2[nj][r] + b2v[nj]);
    }
}

// ---------------------------------------------------------------------------
// Kernel 2: out[b] = q_b @ k_b^T, fp32 out. 64x64 tile, 1024 blocks of 4
// waves -> 4 blocks/CU, 4 waves/SIMD. Wave w computes rows [16w,16w+16).
// Operands are contiguous 16 B fragments from L2-resident q/k (no LDS).
// ---------------------------------------------------------------------------
__global__ __launch_bounds__(256, 4) void bmm_k(
    const __hip_bfloat16* __restrict__ q, const __hip_bfloat16* __restrict__ k,
    float* __restrict__ out)
{
  const int b  = blockIdx.z;
  const int n0 = blockIdx.x * 64;
  const int m0 = blockIdx.y * 64;
  const int t = threadIdx.x;
  const int w = t >> 6, l = t & 63, lg = l >> 4, lm = l & 15;

  const __hip_bfloat16* qb = q + ((size_t)b * MAXN + n0 + w * 16) * OUT_C;
  const __hip_bfloat16* kb = k + ((size_t)b * MAXN + m0) * OUT_C;

  f32x4 acc[4];
  #pragma unroll
  for (int nj = 0; nj < 4; ++nj)
    #pragma unroll
    for (int r = 0; r < 4; ++r) acc[nj][r] = 0.f;

  for (int ks = 0; ks < 8; ++ks) {
    short8 a = *(const short8*)(qb + (size_t)lm * OUT_C + ks * 32 + lg * 8);
    #pragma unroll
    for (int nj = 0; nj < 4; ++nj) {
      short8 bb = *(const short8*)(kb + (size_t)(nj * 16 + lm) * OUT_C + ks * 32 + lg * 8);
      acc[nj] = MFMA16(a, bb, acc[nj]);
    }
  }

  #pragma unroll
  for (int nj = 0; nj < 4; ++nj)
    #pragma unroll
    for (int r = 0; r < 4; ++r) {
      const int nrow = n0 + w * 16 + lg * 4 + r;   // q node (output row)
      const int mcol = m0 + nj * 16 + lm;          // k node (output col)
      out[((size_t)b * MAXN + nrow) * MAXN + mcol] = acc[nj][r];
    }
}

// ---------------------------------------------------------------------------
extern "C" void kernel_launch(void* const* d_in, const int* in_sizes, int n_in,
                              void* d_out, int out_size, void* d_ws, size_t ws_size,
                              hipStream_t stream)
{
  const float* x   = (const float*)d_in[0];
  const int*   fpb = (const int*)d_in[1];
  // d_in[2]=g_node_batches (repeat(arange(16),512) -> pad/split is identity
  // reshape), d_in[3]=num_graphs, d_in[4]=max_nodes.
  const float* Wq_w1  = (const float*)d_in[5];
  const float* Wq_b1  = (const float*)d_in[6];
  const float* Wq_g1  = (const float*)d_in[7];
  const float* Wq_be1 = (const float*)d_in[8];
  const float* Wq_w2  = (const float*)d_in[9];
  const float* Wq_b2  = (const float*)d_in[10];
  const float* Wk_w1  = (const float*)d_in[11];
  const float* Wk_b1  = (const float*)d_in[12];
  const float* Wk_g1  = (const float*)d_in[13];
  const float* Wk_be1 = (const float*)d_in[14];
  const float* Wk_w2  = (const float*)d_in[15];
  const float* Wk_b2  = (const float*)d_in[16];

  __hip_bfloat16* ws = (__hip_bfloat16*)d_ws;
  __hip_bfloat16* P1q  = ws;                 // 131072 bf16 each
  __hip_bfloat16* P1k  = P1q + 131072;
  __hip_bfloat16* P2q  = P1k + 131072;
  __hip_bfloat16* P2k  = P2q + 131072;
  __hip_bfloat16* qo   = P2k + 131072;       // 8192*256
  __hip_bfloat16* ko   = qo + 2097152;
  int* starts = (int*)(ko + 2097152);        // 8193 ints
  float* out = (float*)d_out;

  prelude_k<<<1280, 256, 0, stream>>>(fpb, starts,
      Wq_w1, Wk_w1, Wq_w2, Wk_w2, P1q, P1k, P2q, P2k);
  fused_mlp_k<<<N_NODES / NPB, 512, 0, stream>>>(
      x, starts, P1q, P2q, Wq_b1, Wq_g1, Wq_be1, Wq_b2,
      P1k, P2k, Wk_b1, Wk_g1, Wk_be1, Wk_b2, qo, ko);
  bmm_k<<<dim3(8, 8, NB), 256, 0, stream>>>(qo, ko, out);
}